// Round 10
// baseline (114.883 us; speedup 1.0000x reference)
//
#include <hip/hip_runtime.h>
#include <hip/hip_bf16.h>

#define N 4096
#define D 768
#define LN2 0.69314718055994530942f
#define QSCALE 5.371583f   // sqrt(20 * log2(e)); applied to BOTH inputs -> logits in base-2 domain

typedef __attribute__((ext_vector_type(4))) int   i32x4;
typedef __attribute__((ext_vector_type(8))) int   i32x8;
typedef __attribute__((ext_vector_type(4))) float f32x4;

#define EXP2F(x) __builtin_amdgcn_exp2f(x)   // v_exp_f32: 2^x
#define LOG2F(x) __builtin_amdgcn_logf(x)    // v_log_f32: log2(x)

// global -> LDS direct DMA, 16B per lane, linear dest (wave base + lane*16)
#define GLDS16(g, l) __builtin_amdgcn_global_load_lds( \
    (const __attribute__((address_space(1))) void*)(g), \
    (__attribute__((address_space(3))) void*)(l), 16, 0, 0)

// ws layout (bytes):
//   [0,       3145728)  A fp8 e4m3 (anchors * QSCALE), N*D
//   [3145728, 6291456)  B fp8 e4m3 (positives * QSCALE), N*D
//   [6291456, 6553600)  partial[16][4096] float  (per colTile row sums of 2^s)
//   [6553600, 6569984)  diagS[4096] float        (s2_jj, base-2 logit)
//   [6569984, 6586368)  lastS[4096] float        (s2_{j,N-1})
//   [6586368, 6586496)  blockSums[32] float

__global__ void convert_kernel(const float* __restrict__ A, const float* __restrict__ B,
                               unsigned* __restrict__ Af8, unsigned* __restrict__ Bf8) {
    const int total = N * D / 4;
    int idx = blockIdx.x * blockDim.x + threadIdx.x;
    int stride = gridDim.x * blockDim.x;
    for (int i = idx; i < total; i += stride) {
        float4 a = ((const float4*)A)[i];
        float4 b = ((const float4*)B)[i];
        int pa = __builtin_amdgcn_cvt_pk_fp8_f32(a.x * QSCALE, a.y * QSCALE, 0, 0);
        pa     = __builtin_amdgcn_cvt_pk_fp8_f32(a.z * QSCALE, a.w * QSCALE, pa, 1);
        int pb = __builtin_amdgcn_cvt_pk_fp8_f32(b.x * QSCALE, b.y * QSCALE, 0, 0);
        pb     = __builtin_amdgcn_cvt_pk_fp8_f32(b.z * QSCALE, b.w * QSCALE, pb, 1);
        Af8[i] = (unsigned)pa;
        Bf8[i] = (unsigned)pb;
    }
}

// 256x256 tile, BK=128 (one MX K-block per MFMA), 8 waves (2M x 4N), per-wave
// 128x64 = acc[8][4] of 16x16x128 scaled-MFMA (scales = 1.0 = 0x7F E8M0).
// Wave-tile intensity 87 FLOP/LDS-byte (> 59 breakeven) -> MFMA-dominant.
// Grid = 256 blocks = exactly 1 block/CU, single round.
// Schedule = R5/R9's verified 2-phase counted-vmcnt pipeline (depth 2): per
// iter wait vmcnt(8) (tile t landed; t+1 stays in flight across the barrier),
// compute tile t (compiler-scheduled ds_read/MFMA interleave; no bulk lgkmcnt
// drain -- MFMA data deps + barrier give buffer-overwrite safety), barrier,
// stage tile t+2 into the freed buffer.
// LDS linear (global_load_lds); 16B-chunk XOR-swizzle on global source AND
// fragment ds_read (rule #21). Lane k-window = chunks {hi, hi+4}: each
// ds_read_b128 spreads 64 lanes over all 8 chunks = 2 lanes/bank = free (m136).
// NOTE: plain __launch_bounds__(512) -- R8's (512,2) clamped VGPRs to 128 and
// spilled acc (WRITE_SIZE 190 MB); 8-wave blocks already imply the 256 cap.
__global__ __launch_bounds__(512) void gemm_kernel(const unsigned char* __restrict__ Af8,
                                                   const unsigned char* __restrict__ Bf8,
                                                   float* __restrict__ partial,
                                                   float* __restrict__ diagS,
                                                   float* __restrict__ lastS) {
    __shared__ __align__(16) unsigned char As[2][256 * 128];  // 2 x 32 KB
    __shared__ __align__(16) unsigned char Bs[2][256 * 128];  // 2 x 32 KB
    __shared__ float rowsumL[4][256];                          // 4 KB

    const int t    = threadIdx.x;
    const int bCol = blockIdx.x;
    const int bRow = blockIdx.y;
    const int lane = t & 63;
    const int w    = t >> 6;      // wave 0..7
    const int wm   = w >> 2;      // wave M 0..1 (rows wm*128..+128)
    const int wn   = w & 3;       // wave N 0..3 (cols wn*64..+64)
    const int lr   = lane & 15;
    const int hi   = lane >> 4;   // 0..3

    // staging: thread t covers (row t>>3 within a 64-row round, 16B chunk t&7);
    // source chunk XOR-swizzled so linear LDS holds the swizzled image
    const int srow = t >> 3;            // 0..63
    const int sc   = t & 7;             // 0..7
    const int gcv  = sc ^ (srow & 7);   // swizzled global chunk
    const size_t aOff = (size_t)(bRow * 256 + srow) * D + gcv * 16;
    const size_t bOff = (size_t)(bCol * 256 + srow) * D + gcv * 16;

    f32x4 acc[8][4] = {};
    const int NT = D / 128;  // 6

    union Frag { i32x8 v; i32x4 h[2]; };

#define STAGE(BUF, T) do {                                                             \
    const size_t kb_ = (size_t)(T) * 128;                                              \
    _Pragma("unroll")                                                                  \
    for (int r = 0; r < 4; ++r) {                                                      \
        GLDS16(Af8 + aOff + (size_t)r * 64 * D + kb_, &As[BUF][(r * 64 + w * 8) * 128]); \
        GLDS16(Bf8 + bOff + (size_t)r * 64 * D + kb_, &Bs[BUF][(r * 64 + w * 8) * 128]); \
    }                                                                                  \
} while (0)

// 32B fragment for row ROW (ROW&7 == lr&7 since frag bases are multiples of 16):
// logical chunks {hi, hi+4}, physical = logical ^ (lr&7).
#define LDFRAG(DST, ARRBUF, ROW) do {                                                  \
    (DST).h[0] = *(const i32x4*)&(ARRBUF)[(ROW) * 128 + ((hi ^ (lr & 7)) * 16)];       \
    (DST).h[1] = *(const i32x4*)&(ARRBUF)[(ROW) * 128 + (((hi + 4) ^ (lr & 7)) * 16)]; \
} while (0)

#define ITER(CUR, T, VN, DOSTAGE) do {                                                 \
    asm volatile("s_waitcnt vmcnt(" #VN ")" ::: "memory");                             \
    __builtin_amdgcn_s_barrier();                                                      \
    __builtin_amdgcn_sched_barrier(0);                                                 \
    Frag bfr[4];                                                                       \
    _Pragma("unroll")                                                                  \
    for (int nf = 0; nf < 4; ++nf)                                                     \
        LDFRAG(bfr[nf], Bs[CUR], wn * 64 + nf * 16 + lr);                              \
    __builtin_amdgcn_s_setprio(1);                                                     \
    _Pragma("unroll")                                                                  \
    for (int mf = 0; mf < 8; ++mf) {                                                   \
        Frag a8;                                                                       \
        LDFRAG(a8, As[CUR], wm * 128 + mf * 16 + lr);                                  \
        _Pragma("unroll")                                                              \
        for (int nf = 0; nf < 4; ++nf)                                                 \
            acc[mf][nf] = __builtin_amdgcn_mfma_scale_f32_16x16x128_f8f6f4(            \
                a8.v, bfr[nf].v, acc[mf][nf], 0, 0, 0, 0x7F7F7F7F, 0, 0x7F7F7F7F);     \
    }                                                                                  \
    __builtin_amdgcn_s_setprio(0);                                                     \
    __builtin_amdgcn_sched_barrier(0);                                                 \
    __builtin_amdgcn_s_barrier();                                                      \
    __builtin_amdgcn_sched_barrier(0);                                                 \
    if (DOSTAGE) STAGE(CUR, (T) + 2);                                                  \
} while (0)

    // prologue: tiles 0 and 1 in flight (16 outstanding vmem/wave)
    STAGE(0, 0);
    STAGE(1, 1);

    for (int tt = 0; tt < NT - 2; tt += 2) {   // tt = 0,2 -> stages tiles 2..5
        ITER(0, tt,     8, 1);
        ITER(1, tt + 1, 8, 1);
    }
    ITER(0, NT - 2, 8, 0);                     // tile 5 still in flight
    ITER(1, NT - 1, 0, 0);                     // final drain
#undef ITER
#undef LDFRAG
#undef STAGE

    // C/D layout (shape-determined, = 16x16 bf16: col = lane&15, row = hi*4+reg)
    const int rifb = hi * 4;

    // diagonal capture: global row == global col (compile-time acc indices)
    if (bRow == bCol) {
        #pragma unroll
        for (int mf = 0; mf < 8; ++mf)
            #pragma unroll
            for (int nf = 0; nf < 4; ++nf)
                if (wm * 128 + mf * 16 == wn * 64 + nf * 16) {
                    #pragma unroll
                    for (int reg = 0; reg < 4; ++reg)
                        if (lr == rifb + reg)
                            diagS[bRow * 256 + wm * 128 + mf * 16 + rifb + reg] = acc[mf][nf][reg];
                }
    }

    // last-column capture: col N-1 -> bCol==15, wn==3, nf==3, lr==15
    if (bCol == (N / 256 - 1) && wn == 3 && lr == 15) {
        #pragma unroll
        for (int mf = 0; mf < 8; ++mf)
            #pragma unroll
            for (int reg = 0; reg < 4; ++reg)
                lastS[bRow * 256 + wm * 128 + mf * 16 + rifb + reg] = acc[mf][3][reg];
    }

    // 2^s over the tile, row-sum across the wave's 64 columns
    #pragma unroll
    for (int mf = 0; mf < 8; ++mf) {
        #pragma unroll
        for (int reg = 0; reg < 4; ++reg) {
            float s = EXP2F(acc[mf][0][reg]) + EXP2F(acc[mf][1][reg]) +
                      EXP2F(acc[mf][2][reg]) + EXP2F(acc[mf][3][reg]);
            s += __shfl_xor(s, 1);
            s += __shfl_xor(s, 2);
            s += __shfl_xor(s, 4);
            s += __shfl_xor(s, 8);
            if (lr == 0) rowsumL[wn][wm * 128 + mf * 16 + rifb + reg] = s;
        }
    }
    __syncthreads();
    if (t < 256)
        partial[(size_t)bCol * N + bRow * 256 + t] =
            rowsumL[0][t] + rowsumL[1][t] + rowsumL[2][t] + rowsumL[3][t];
}

__global__ void rowloss_kernel(const float* __restrict__ partial, const float* __restrict__ diagS,
                               const float* __restrict__ lastS, float* __restrict__ blockSums) {
    const int j = blockIdx.x * 128 + threadIdx.x;
    float rs = 0.0f;
    #pragma unroll
    for (int tI = 0; tI < 16; ++tI) rs += partial[(size_t)tI * N + j];
    float denom = rs + EXP2F(diagS[j]);
    float lossj = LN2 * (LOG2F(denom) - lastS[j]);
    #pragma unroll
    for (int off = 1; off < 64; off <<= 1) lossj += __shfl_xor(lossj, off);
    __shared__ float ws2[2];
    if ((threadIdx.x & 63) == 0) ws2[threadIdx.x >> 6] = lossj;
    __syncthreads();
    if (threadIdx.x == 0) blockSums[blockIdx.x] = ws2[0] + ws2[1];
}

__global__ void final_kernel(const float* __restrict__ blockSums, float* __restrict__ out) {
    float v = (threadIdx.x < 32) ? blockSums[threadIdx.x] : 0.0f;
    #pragma unroll
    for (int off = 1; off < 32; off <<= 1) v += __shfl_xor(v, off);
    if (threadIdx.x == 0) out[0] = v;
}

extern "C" void kernel_launch(void* const* d_in, const int* in_sizes, int n_in,
                              void* d_out, int out_size, void* d_ws, size_t ws_size,
                              hipStream_t stream) {
    const float* A = (const float*)d_in[0];
    const float* B = (const float*)d_in[1];
    float* out = (float*)d_out;
    char* ws = (char*)d_ws;

    unsigned char* Af8 = (unsigned char*)(ws);
    unsigned char* Bf8 = (unsigned char*)(ws + 3145728);
    float* partial     = (float*)(ws + 6291456);
    float* diagS       = (float*)(ws + 6553600);
    float* lastS       = (float*)(ws + 6569984);
    float* blockSums   = (float*)(ws + 6586368);

    convert_kernel<<<1024, 256, 0, stream>>>(A, B, (unsigned*)Af8, (unsigned*)Bf8);
    gemm_kernel<<<dim3(16, 16), 512, 0, stream>>>(Af8, Bf8, partial, diagS, lastS);
    rowloss_kernel<<<32, 128, 0, stream>>>(partial, diagS, lastS, blockSums);
    final_kernel<<<1, 64, 0, stream>>>(blockSums, out);
}

// Round 11
// 36.069 us; speedup vs baseline: 3.1851x; 3.1851x over previous
//
#include <hip/hip_runtime.h>
#include <hip/hip_bf16.h>

#define N 4096
#define D 768
#define LN2 0.69314718055994530942f
#define QSCALE 5.371583f   // sqrt(20 * log2(e)); applied to BOTH inputs -> logits in base-2 domain

typedef __attribute__((ext_vector_type(4))) int   i32x4;
typedef __attribute__((ext_vector_type(8))) int   i32x8;
typedef __attribute__((ext_vector_type(4))) float f32x4;

#define EXP2F(x) __builtin_amdgcn_exp2f(x)   // v_exp_f32: 2^x
#define LOG2F(x) __builtin_amdgcn_logf(x)    // v_log_f32: log2(x)

// global -> LDS direct DMA, 16B per lane, linear dest (wave base + lane*16)
#define GLDS16(g, l) __builtin_amdgcn_global_load_lds( \
    (const __attribute__((address_space(1))) void*)(g), \
    (__attribute__((address_space(3))) void*)(l), 16, 0, 0)

// ws layout (bytes):
//   [0,       3145728)  A fp8 e4m3 (anchors * QSCALE), N*D
//   [3145728, 6291456)  B fp8 e4m3 (positives * QSCALE), N*D
//   [6291456, 6815744)  partial[32][4096] float  (per colTile row sums of 2^s)
//   [6815744, 6832128)  diagS[4096] float        (s2_jj, base-2 logit)
//   [6832128, 6848512)  lastS[4096] float        (s2_{j,N-1})
//   [6848512, 6848640)  blockSums[32] float

__global__ void convert_kernel(const float* __restrict__ A, const float* __restrict__ B,
                               unsigned* __restrict__ Af8, unsigned* __restrict__ Bf8) {
    const int total = N * D / 4;
    int idx = blockIdx.x * blockDim.x + threadIdx.x;
    int stride = gridDim.x * blockDim.x;
    for (int i = idx; i < total; i += stride) {
        float4 a = ((const float4*)A)[i];
        float4 b = ((const float4*)B)[i];
        int pa = __builtin_amdgcn_cvt_pk_fp8_f32(a.x * QSCALE, a.y * QSCALE, 0, 0);
        pa     = __builtin_amdgcn_cvt_pk_fp8_f32(a.z * QSCALE, a.w * QSCALE, pa, 1);
        int pb = __builtin_amdgcn_cvt_pk_fp8_f32(b.x * QSCALE, b.y * QSCALE, 0, 0);
        pb     = __builtin_amdgcn_cvt_pk_fp8_f32(b.z * QSCALE, b.w * QSCALE, pb, 1);
        Af8[i] = (unsigned)pa;
        Bf8[i] = (unsigned)pb;
    }
}

// 128x128 tile, BK=128 (one MX K-block per MFMA), 4 waves (2x2), per-wave
// 64x64 = acc[4][4] of 16x16x128 scaled-MFMA (scales = 1.0 = 0x7F E8M0) —
// EXACTLY the verified R9 kernel (36.4 us, absmax 0), plus ONE change:
// bijective XCD-chunked block swizzle (T1). Without it, each XCD's staging
// working set (~6 MB) overflows its private 4 MB L2 and the 201 MB of panel
// staging is served at L3/HBM-class BW (~the observed 24 us gemm wall).
// With it, each XCD (bid&7, matching HW round-robin dispatch) owns an 8x16
// block rectangle: A-rows 768 KB + B-cols 1.5 MB = 2.3 MB < 4 MB L2.
// Schedule: R5/R9's 2-phase counted-vmcnt pipeline (depth 2): per iter wait
// vmcnt(8) (tile t landed; t+1 stays in flight across the barrier), compute
// tile t, lgkmcnt(0)+barrier, stage tile t+2 into the freed buffer.
// LDS linear (global_load_lds); 16B-chunk XOR-swizzle on global source AND
// fragment ds_read (rule #21). Lane k-window = chunks {hi, hi+4}: each
// ds_read_b128 spreads 64 lanes over all 8 chunks = 2 lanes/bank = free (m136).
__global__ __launch_bounds__(256) void gemm_kernel(const unsigned char* __restrict__ Af8,
                                                   const unsigned char* __restrict__ Bf8,
                                                   float* __restrict__ partial,
                                                   float* __restrict__ diagS,
                                                   float* __restrict__ lastS) {
    __shared__ __align__(16) unsigned char As[2][128 * 128];  // 2 x 16 KB
    __shared__ __align__(16) unsigned char Bs[2][128 * 128];  // 2 x 16 KB
    __shared__ float rowsum2[2][128];

    const int t    = threadIdx.x;
    // XCD-chunked bijective swizzle: xcd = bid&7 (HW round-robin), each XCD
    // owns an 8-row x 16-col rectangle of the 32x32 block grid.
    const int bid  = blockIdx.x;
    const int xcd  = bid & 7;
    const int ii   = bid >> 3;                        // 0..127
    const int bRow = ((xcd >> 1) << 3) + (ii >> 4);   // {0,8,16,24} + 0..7
    const int bCol = ((xcd & 1) << 4) + (ii & 15);    // {0,16} + 0..15
    const int lane = t & 63;
    const int w    = t >> 6;      // wave 0..3
    const int wr   = w >> 1;      // wave row 0..1
    const int wc   = w & 1;       // wave col 0..1
    const int lr   = lane & 15;
    const int hi   = lane >> 4;   // 0..3

    // staging: thread t covers (row t>>3 of a 32-row round, 16B chunk t&7);
    // source chunk XOR-swizzled so linear LDS holds the swizzled image
    const int srow = t >> 3;            // 0..31
    const int sc   = t & 7;             // 0..7
    const int gcv  = sc ^ (srow & 7);   // swizzled global chunk
    const size_t aOff = (size_t)(bRow * 128 + srow) * D + gcv * 16;
    const size_t bOff = (size_t)(bCol * 128 + srow) * D + gcv * 16;

    f32x4 acc[4][4] = {};
    const int NT = D / 128;  // 6

    union Frag { i32x8 v; i32x4 h[2]; };

#define STAGE(BUF, T) do {                                                              \
    const size_t kb_ = (size_t)(T) * 128;                                               \
    _Pragma("unroll")                                                                   \
    for (int inst = 0; inst < 4; ++inst) {                                              \
        GLDS16(Af8 + aOff + (size_t)inst * 32 * D + kb_, &As[BUF][inst * 4096 + w * 1024]); \
        GLDS16(Bf8 + bOff + (size_t)inst * 32 * D + kb_, &Bs[BUF][inst * 4096 + w * 1024]); \
    }                                                                                   \
} while (0)

// 32B fragment for row ROW (ROW&7 == lr&7 since frag bases are multiples of 16):
// logical chunks {hi, hi+4}, physical = logical ^ (lr&7).
#define LDFRAG(DST, ARRBUF, ROW) do {                                                   \
    (DST).h[0] = *(const i32x4*)&(ARRBUF)[(ROW) * 128 + ((hi ^ (lr & 7)) * 16)];        \
    (DST).h[1] = *(const i32x4*)&(ARRBUF)[(ROW) * 128 + (((hi + 4) ^ (lr & 7)) * 16)];  \
} while (0)

#define ITER(CUR, T, VN, DOSTAGE) do {                                                  \
    asm volatile("s_waitcnt vmcnt(" #VN ")" ::: "memory");                              \
    __builtin_amdgcn_s_barrier();                                                       \
    __builtin_amdgcn_sched_barrier(0);                                                  \
    Frag bfr[4];                                                                        \
    _Pragma("unroll")                                                                   \
    for (int nf = 0; nf < 4; ++nf)                                                      \
        LDFRAG(bfr[nf], Bs[CUR], wc * 64 + nf * 16 + lr);                               \
    __builtin_amdgcn_s_setprio(1);                                                      \
    _Pragma("unroll")                                                                   \
    for (int mf = 0; mf < 4; ++mf) {                                                    \
        Frag a8;                                                                        \
        LDFRAG(a8, As[CUR], wr * 64 + mf * 16 + lr);                                    \
        _Pragma("unroll")                                                               \
        for (int nf = 0; nf < 4; ++nf)                                                  \
            acc[mf][nf] = __builtin_amdgcn_mfma_scale_f32_16x16x128_f8f6f4(             \
                a8.v, bfr[nf].v, acc[mf][nf], 0, 0, 0, 0x7F7F7F7F, 0, 0x7F7F7F7F);      \
    }                                                                                   \
    __builtin_amdgcn_s_setprio(0);                                                      \
    asm volatile("s_waitcnt lgkmcnt(0)" ::: "memory");                                  \
    __builtin_amdgcn_sched_barrier(0);                                                  \
    __builtin_amdgcn_s_barrier();                                                       \
    __builtin_amdgcn_sched_barrier(0);                                                  \
    if (DOSTAGE) STAGE(CUR, (T) + 2);                                                   \
} while (0)

    // prologue: tiles 0 and 1 in flight (16 outstanding vmem/wave)
    STAGE(0, 0);
    STAGE(1, 1);

    for (int tt = 0; tt < NT - 2; tt += 2) {   // tt = 0,2 -> stages tiles 2..5
        ITER(0, tt,     8, 1);
        ITER(1, tt + 1, 8, 1);
    }
    ITER(0, NT - 2, 8, 0);                     // tile 5 still in flight
    ITER(1, NT - 1, 0, 0);                     // final drain
#undef ITER
#undef LDFRAG
#undef STAGE

    // C/D layout (shape-determined, = 16x16 bf16: col = lane&15, row = hi*4+reg)
    const int rifb = hi * 4;

    // diagonal capture: s_jj lives in frags (m,m) of waves with wr==wc
    if (bRow == bCol && wr == wc) {
        #pragma unroll
        for (int mf = 0; mf < 4; ++mf)
            #pragma unroll
            for (int reg = 0; reg < 4; ++reg)
                if (lr == rifb + reg)
                    diagS[bRow * 128 + wr * 64 + mf * 16 + rifb + reg] = acc[mf][mf][reg];
    }

    // last-column capture: col N-1 -> bCol==31, wc==1, nf==3, lr==15
    if (bCol == (N / 128 - 1) && wc == 1 && lr == 15) {
        #pragma unroll
        for (int mf = 0; mf < 4; ++mf)
            #pragma unroll
            for (int reg = 0; reg < 4; ++reg)
                lastS[bRow * 128 + wr * 64 + mf * 16 + rifb + reg] = acc[mf][3][reg];
    }

    // 2^s over the tile, row-sum across the wave's 64 columns
    #pragma unroll
    for (int mf = 0; mf < 4; ++mf) {
        #pragma unroll
        for (int reg = 0; reg < 4; ++reg) {
            float s = EXP2F(acc[mf][0][reg]) + EXP2F(acc[mf][1][reg]) +
                      EXP2F(acc[mf][2][reg]) + EXP2F(acc[mf][3][reg]);
            s += __shfl_xor(s, 1);
            s += __shfl_xor(s, 2);
            s += __shfl_xor(s, 4);
            s += __shfl_xor(s, 8);
            if (lr == 0) rowsum2[wc][wr * 64 + mf * 16 + rifb + reg] = s;
        }
    }
    __syncthreads();
    if (t < 128) partial[(size_t)bCol * N + bRow * 128 + t] = rowsum2[0][t] + rowsum2[1][t];
}

__global__ void rowloss_kernel(const float* __restrict__ partial, const float* __restrict__ diagS,
                               const float* __restrict__ lastS, float* __restrict__ blockSums) {
    const int j = blockIdx.x * 128 + threadIdx.x;
    float rs = 0.0f;
    #pragma unroll
    for (int tI = 0; tI < 32; ++tI) rs += partial[(size_t)tI * N + j];
    float denom = rs + EXP2F(diagS[j]);
    float lossj = LN2 * (LOG2F(denom) - lastS[j]);
    #pragma unroll
    for (int off = 1; off < 64; off <<= 1) lossj += __shfl_xor(lossj, off);
    __shared__ float ws2[2];
    if ((threadIdx.x & 63) == 0) ws2[threadIdx.x >> 6] = lossj;
    __syncthreads();
    if (threadIdx.x == 0) blockSums[blockIdx.x] = ws2[0] + ws2[1];
}

__global__ void final_kernel(const float* __restrict__ blockSums, float* __restrict__ out) {
    float v = (threadIdx.x < 32) ? blockSums[threadIdx.x] : 0.0f;
    #pragma unroll
    for (int off = 1; off < 32; off <<= 1) v += __shfl_xor(v, off);
    if (threadIdx.x == 0) out[0] = v;
}

extern "C" void kernel_launch(void* const* d_in, const int* in_sizes, int n_in,
                              void* d_out, int out_size, void* d_ws, size_t ws_size,
                              hipStream_t stream) {
    const float* A = (const float*)d_in[0];
    const float* B = (const float*)d_in[1];
    float* out = (float*)d_out;
    char* ws = (char*)d_ws;

    unsigned char* Af8 = (unsigned char*)(ws);
    unsigned char* Bf8 = (unsigned char*)(ws + 3145728);
    float* partial     = (float*)(ws + 6291456);
    float* diagS       = (float*)(ws + 6815744);
    float* lastS       = (float*)(ws + 6832128);
    float* blockSums   = (float*)(ws + 6848512);

    convert_kernel<<<1024, 256, 0, stream>>>(A, B, (unsigned*)Af8, (unsigned*)Bf8);
    gemm_kernel<<<1024, 256, 0, stream>>>(Af8, Bf8, partial, diagS, lastS);
    rowloss_kernel<<<32, 128, 0, stream>>>(partial, diagS, lastS, blockSums);
    final_kernel<<<1, 64, 0, stream>>>(blockSums, out);
}